// Round 19
// baseline (438.116 us; speedup 1.0000x reference)
//
#include <hip/hip_runtime.h>
#include <math.h>

#define BB 1024
#define TT 512
#define L2E 1.4426950408889634f

typedef __attribute__((ext_vector_type(4))) short  bfx4;
typedef __attribute__((ext_vector_type(8))) short  bfx8;
typedef __attribute__((ext_vector_type(2))) int    int2v;
typedef __attribute__((ext_vector_type(4))) int    int4v;
typedef __attribute__((ext_vector_type(4))) float  floatx4;

__device__ __forceinline__ float fast_rcp(float x){ return __builtin_amdgcn_rcpf(x); }
__device__ __forceinline__ float exp2f_(float x){ return __builtin_amdgcn_exp2f(x); }
__device__ __forceinline__ float sigmoidf_(float x){ return fast_rcp(1.0f + __expf(-x)); }
__device__ __forceinline__ unsigned short f2bf(float f){
    unsigned u = __builtin_bit_cast(unsigned, f);
    u += 0x7fffu + ((u >> 16) & 1u);
    return (unsigned short)(u >> 16);
}
__device__ __forceinline__ float bf2f(unsigned short u){
    return __builtin_bit_cast(float, ((unsigned)u) << 16);
}
__device__ __forceinline__ int cvt_pk_bf16(float lo, float hi){
    int r; asm("v_cvt_pk_bf16_f32 %0, %1, %2" : "=v"(r) : "v"(lo), "v"(hi)); return r;
}
__device__ __forceinline__ floatx4 mfma16(bfx4 a, bfx4 b, floatx4 c){
    return __builtin_amdgcn_mfma_f32_16x16x16bf16_1k(a, b, c, 0, 0, 0);
}
__device__ __forceinline__ floatx4 mfma32(bfx8 a, bfx8 b, floatx4 c){
    return __builtin_amdgcn_mfma_f32_16x16x32_bf16(a, b, c, 0, 0, 0);
}
// Non-temporal streaming access: write-once/read-once inter-kernel streams
// (h1, out2) bypass the per-XCD L2 so the consumer kernel doesn't pay
// cross-XCD dirty-line writeback-then-fetch.
__device__ __forceinline__ void nt_store(int2v v, unsigned short* p){
    __builtin_nontemporal_store(v, (int2v*)p);
}
__device__ __forceinline__ bfx8 nt_load8(const unsigned short* p){
    return __builtin_nontemporal_load((const bfx8*)p);
}

// sigma(q,j): k-slot order of the feedback B-frag (R10-verified)
__device__ __forceinline__ int sigma_k(int q, int j){
    return (j < 4) ? (q*4 + j) : (16 + q*4 + (j - 4));
}

// lgkm-only workgroup barrier (R1/R14-verified, R16 pinned form): does NOT
// drain vmcnt, so the named-phase global prefetch stays in flight.
__device__ __forceinline__ void lgkm_barrier(){
    __builtin_amdgcn_sched_barrier(0);
    asm volatile("s_waitcnt lgkmcnt(0)" ::: "memory");
    __builtin_amdgcn_s_barrier();
    __builtin_amdgcn_sched_barrier(0);
}

// ---------------------------------------------------------------------------
// biGRU recurrence, GT-SPLIT across 2 waves (R14/R16-exact): wave w owns
// gate-tile gt=w. Lane-aligned h-exchange: one ds_write_b64 + lgkm-barrier +
// ds_read_b64 per step, double-buffered. h1 stores are NON-TEMPORAL.
// ---------------------------------------------------------------------------
__global__ __launch_bounds__(128, 1) void gru_l0(
    const float* __restrict__ x,      // (B,T,4) f32
    const float* __restrict__ w_ih,   // (2,96,4)
    const float* __restrict__ w_hh,   // (2,96,32)
    const float* __restrict__ b_ih,   // (2,96)
    const float* __restrict__ b_hh,   // (2,96)
    unsigned short* __restrict__ h1)  // (B,T,64) bf16
{
    const int tile = blockIdx.x;      // 0..127
    const int bt   = tile >> 1;
    const int d    = tile & 1;
    const int b0   = bt * 16;
    const int w    = threadIdx.x >> 6;   // owned gt
    const int L    = threadIdx.x & 63;
    const int c    = L & 15;
    const int q    = L >> 4;

    bfx8 whh[3];
    bfx4 wih[3];
    #pragma unroll
    for (int g = 0; g < 3; ++g){
        const float sc = (g == 2) ? (2.0f * L2E) : L2E;
        const int row = d*96 + g*32 + w*16 + c;
        bfx8 f;
        #pragma unroll
        for (int j = 0; j < 8; ++j)
            f[j] = f2bf(w_hh[(size_t)row*32 + sigma_k(q, j)] * sc);
        whh[g] = f;
        bfx4 fi = {0,0,0,0};
        if (q == 0){
            #pragma unroll
            for (int j = 0; j < 4; ++j) fi[j] = f2bf(w_ih[(size_t)row*4 + j] * sc);
        }
        wih[g] = fi;
    }
    floatx4 cbr, cbz, cbni, cbhn;
    #pragma unroll
    for (int r = 0; r < 4; ++r){
        const int gidx = d*96 + w*16 + q*4 + r;
        cbr[r]  = L2E * (b_ih[gidx]      + b_hh[gidx]);
        cbz[r]  = L2E * (b_ih[gidx + 32] + b_hh[gidx + 32]);
        cbni[r] = 2.0f * L2E * b_ih[gidx + 64];
        cbhn[r] = 2.0f * L2E * b_hh[gidx + 64];
    }

    __shared__ int2v hx[2][2][64];    // [buf][wave][lane], 2 KB

    float hr[4] = {0.f,0.f,0.f,0.f};
    bfx8 ahc = {0,0,0,0,0,0,0,0};     // full h_{t-1} B-frag (both halves)

    const size_t xrow = (size_t)(b0 + c) * TT;
    float4 xq[4] = {{0,0,0,0},{0,0,0,0},{0,0,0,0},{0,0,0,0}};
    if (q == 0){
        #pragma unroll
        for (int p = 0; p < 4; ++p)
            xq[p] = *(const float4*)(x + (xrow + (d ? TT-1-p : p))*4);
    }

    for (int tb = 0; tb < TT; tb += 4){
        #pragma unroll
        for (int p = 0; p < 4; ++p){
            const int t = tb + p;
            bfx4 ax = {0,0,0,0};
            if (q == 0){
                int2v a; a[0] = cvt_pk_bf16(xq[p].x, xq[p].y); a[1] = cvt_pk_bf16(xq[p].z, xq[p].w);
                ax = __builtin_bit_cast(bfx4, a);
            }
            if (q == 0 && t + 4 < TT)
                xq[p] = *(const float4*)(x + (xrow + (d ? TT-5-t : t+4))*4);

            floatx4 racc  = mfma16(wih[0], ax, cbr);
            floatx4 zacc  = mfma16(wih[1], ax, cbz);
            floatx4 xnacc = mfma16(wih[2], ax, cbni);
            racc          = mfma32(whh[0], ahc, racc);
            zacc          = mfma32(whh[1], ahc, zacc);
            floatx4 hnacc = mfma32(whh[2], ahc, cbhn);

            #pragma unroll
            for (int r = 0; r < 4; ++r){
                const float pp = 1.0f + exp2f_(-racc[r]);
                const float qd = 1.0f + exp2f_(-zacc[r]);
                const float s  = fast_rcp(pp * qd);
                const float rg = s * qd;
                const float zg = s * pp;
                const float e2 = exp2f_(xnacc[r] + rg * hnacc[r]);
                const float ng = 1.0f - 2.0f * fast_rcp(e2 + 1.0f);
                hr[r] = ng + zg * (hr[r] - ng);
            }
            int2v own;
            own[0] = cvt_pk_bf16(hr[0], hr[1]);
            own[1] = cvt_pk_bf16(hr[2], hr[3]);

            const int tx = d ? (TT-1-t) : t;
            nt_store(own, &h1[((size_t)(b0 + c)*TT + tx)*64 + d*32 + w*16 + q*4]);

            const int wb = t & 1;
            hx[wb][w][L] = own;
            lgkm_barrier();
            const int2v oth = hx[wb][1 - w][L];

            int4v comb;
            if (w == 0){ comb[0] = own[0]; comb[1] = own[1]; comb[2] = oth[0]; comb[3] = oth[1]; }
            else       { comb[0] = oth[0]; comb[1] = oth[1]; comb[2] = own[0]; comb[3] = own[1]; }
            ahc = __builtin_bit_cast(bfx8, comb);
        }
    }
}

// ---------------------------------------------------------------------------
// Layer 1, gt-split (R16-exact structure): per wave 6 K32 x-projection MFMAs
// with 4-phase named prefetch (h1 reads NON-TEMPORAL) + 3 sigma-K32 h-side
// MFMAs; out2 stores NON-TEMPORAL; same lane-aligned LDS h-exchange.
// ---------------------------------------------------------------------------
__global__ __launch_bounds__(128, 1) void gru_l1(
    const unsigned short* __restrict__ h1,   // (B,T,64) bf16
    const float* __restrict__ w_ih,   // (2,96,64)
    const float* __restrict__ w_hh,   // (2,96,32)
    const float* __restrict__ b_ih,   // (2,96)
    const float* __restrict__ b_hh,   // (2,96)
    unsigned short* __restrict__ out2) // (B,T,64) bf16
{
    const int tile = blockIdx.x;
    const int bt   = tile >> 1;
    const int d    = tile & 1;
    const int b0   = bt * 16;
    const int w    = threadIdx.x >> 6;
    const int L    = threadIdx.x & 63;
    const int c    = L & 15;
    const int q    = L >> 4;

    bfx8 whh[3], wi0[3], wi1[3];
    #pragma unroll
    for (int g = 0; g < 3; ++g){
        const float sc = (g == 2) ? (2.0f * L2E) : L2E;
        const int row = d*96 + g*32 + w*16 + c;
        bfx8 f, g0, g1;
        #pragma unroll
        for (int j = 0; j < 8; ++j){
            f[j]  = f2bf(w_hh[(size_t)row*32 + sigma_k(q, j)] * sc);
            g0[j] = f2bf(w_ih[(size_t)row*64 +      q*8 + j] * sc);
            g1[j] = f2bf(w_ih[(size_t)row*64 + 32 + q*8 + j] * sc);
        }
        whh[g] = f; wi0[g] = g0; wi1[g] = g1;
    }
    floatx4 cbr, cbz, cbni, cbhn;
    #pragma unroll
    for (int r = 0; r < 4; ++r){
        const int gidx = d*96 + w*16 + q*4 + r;
        cbr[r]  = L2E * (b_ih[gidx]      + b_hh[gidx]);
        cbz[r]  = L2E * (b_ih[gidx + 32] + b_hh[gidx + 32]);
        cbni[r] = 2.0f * L2E * b_ih[gidx + 64];
        cbhn[r] = 2.0f * L2E * b_hh[gidx + 64];
    }

    __shared__ int2v hx[2][2][64];

    float hr[4] = {0.f,0.f,0.f,0.f};
    bfx8 ahc = {0,0,0,0,0,0,0,0};

    const size_t arow = (size_t)(b0 + c) * TT;
    bfx8 A0[4], A1[4];
    #pragma unroll
    for (int p = 0; p < 4; ++p){
        const int tx = d ? TT-1-p : p;
        A0[p] = nt_load8(&h1[(arow + tx)*64 +      q*8]);
        A1[p] = nt_load8(&h1[(arow + tx)*64 + 32 + q*8]);
    }

    for (int tb = 0; tb < TT; tb += 4){
        #pragma unroll
        for (int p = 0; p < 4; ++p){
            const int t = tb + p;

            floatx4 racc  = mfma32(wi0[0], A0[p], cbr);
            racc          = mfma32(wi1[0], A1[p], racc);
            floatx4 zacc  = mfma32(wi0[1], A0[p], cbz);
            zacc          = mfma32(wi1[1], A1[p], zacc);
            floatx4 xnacc = mfma32(wi0[2], A0[p], cbni);
            xnacc         = mfma32(wi1[2], A1[p], xnacc);

            if (t + 4 < TT){
                const int tx4 = d ? (TT-5-t) : (t+4);
                A0[p] = nt_load8(&h1[(arow + tx4)*64 +      q*8]);
                A1[p] = nt_load8(&h1[(arow + tx4)*64 + 32 + q*8]);
            }

            racc          = mfma32(whh[0], ahc, racc);
            zacc          = mfma32(whh[1], ahc, zacc);
            floatx4 hnacc = mfma32(whh[2], ahc, cbhn);

            #pragma unroll
            for (int r = 0; r < 4; ++r){
                const float pp = 1.0f + exp2f_(-racc[r]);
                const float qd = 1.0f + exp2f_(-zacc[r]);
                const float s  = fast_rcp(pp * qd);
                const float rg = s * qd;
                const float zg = s * pp;
                const float e2 = exp2f_(xnacc[r] + rg * hnacc[r]);
                const float ng = 1.0f - 2.0f * fast_rcp(e2 + 1.0f);
                hr[r] = ng + zg * (hr[r] - ng);
            }
            int2v own;
            own[0] = cvt_pk_bf16(hr[0], hr[1]);
            own[1] = cvt_pk_bf16(hr[2], hr[3]);

            const int tx = d ? (TT-1-t) : t;
            nt_store(own, &out2[((size_t)(b0 + c)*TT + tx)*64 + d*32 + w*16 + q*4]);

            const int wb = t & 1;
            hx[wb][w][L] = own;
            lgkm_barrier();
            const int2v oth = hx[wb][1 - w][L];

            int4v comb;
            if (w == 0){ comb[0] = own[0]; comb[1] = own[1]; comb[2] = oth[0]; comb[3] = oth[1]; }
            else       { comb[0] = oth[0]; comb[1] = oth[1]; comb[2] = own[0]; comb[3] = own[1]; }
            ahc = __builtin_bit_cast(bfx8, comb);
        }
    }
}

// ---------------------------------------------------------------------------
// Attention pooling + FC + sigmoid, v5 (R16-exact structure): one-pass online
// softmax, transposed lane mapping (8 lanes/row, 16B loads, 3-shfl reduce) +
// 4-phase NAMED prefetch; out2 reads NON-TEMPORAL (read-once stream).
// ---------------------------------------------------------------------------
__global__ __launch_bounds__(256) void attn_fc(
    const unsigned short* __restrict__ out2, // (B,T,64) bf16
    const float* __restrict__ attn_w, const float* __restrict__ attn_b,
    const float* __restrict__ fc_w,   const float* __restrict__ fc_b,
    float* __restrict__ out)
{
    const int b    = blockIdx.x;
    const int tid  = threadIdx.x;
    const int wave = tid >> 6;      // 0..3
    const int lane = tid & 63;
    const int sub  = lane >> 3;     // row-slot within wave, 0..7
    const int cg   = lane & 7;      // channel-group, 0..7
    const int st   = wave*8 + sub;  // stream id, 0..31

    __shared__ float m_sh[32], s_sh[32];
    __shared__ float acc_sh[32][64];

    float aw[8];
    #pragma unroll
    for (int j = 0; j < 8; ++j) aw[j] = attn_w[cg*8 + j];
    const float ab = attn_b[0];

    float m = -INFINITY, s = 0.0f;
    float acc[8] = {0,0,0,0,0,0,0,0};

    const unsigned short* base = &out2[(size_t)b*TT*64 + cg*8];
    bfx8 vq[4];
    #pragma unroll
    for (int p = 0; p < 4; ++p) vq[p] = nt_load8(base + (size_t)(st + 32*p)*64);

    for (int ib = 0; ib < 4; ++ib){
        #pragma unroll
        for (int p = 0; p < 4; ++p){
            const int it = ib*4 + p;
            const bfx8 v8 = vq[p];
            if (it + 4 < 16) vq[p] = nt_load8(base + (size_t)(st + 32*(it+4))*64);
            float v[8];
            #pragma unroll
            for (int j = 0; j < 8; ++j) v[j] = bf2f((unsigned short)v8[j]);
            float p_ = v[0]*aw[0];
            #pragma unroll
            for (int j = 1; j < 8; ++j) p_ += v[j]*aw[j];
            p_ += __shfl_xor(p_, 1, 64);
            p_ += __shfl_xor(p_, 2, 64);
            p_ += __shfl_xor(p_, 4, 64);
            const float logit = p_ + ab;
            const float nm = fmaxf(m, logit);
            const float cs = exp2f_((m - nm) * L2E);
            const float ce = exp2f_((logit - nm) * L2E);
            s = s * cs + ce;
            #pragma unroll
            for (int j = 0; j < 8; ++j) acc[j] = acc[j]*cs + ce*v[j];
            m = nm;
        }
    }
    if (cg == 0){ m_sh[st] = m; s_sh[st] = s; }
    #pragma unroll
    for (int j = 0; j < 8; ++j) acc_sh[st][cg*8 + j] = acc[j];
    __syncthreads();

    if (wave == 0){
        float M = m_sh[0];
        #pragma unroll
        for (int w = 1; w < 32; ++w) M = fmaxf(M, m_sh[w]);
        float S = 0.0f, ctx = 0.0f;
        #pragma unroll 4
        for (int w = 0; w < 32; ++w){
            const float cw = exp2f_((m_sh[w] - M) * L2E);
            S   += s_sh[w] * cw;
            ctx += acc_sh[w][lane] * cw;
        }
        float v = ctx * fast_rcp(S) * fc_w[lane];
        #pragma unroll
        for (int off = 32; off > 0; off >>= 1) v += __shfl_xor(v, off, 64);
        if (lane == 0) out[b] = sigmoidf_(v + fc_b[0]);
    }
}

extern "C" void kernel_launch(void* const* d_in, const int* in_sizes, int n_in,
                              void* d_out, int out_size, void* d_ws, size_t ws_size,
                              hipStream_t stream) {
    (void)in_sizes; (void)n_in; (void)out_size; (void)ws_size;
    const float* x      = (const float*)d_in[0];
    const float* w_ih0  = (const float*)d_in[1];
    const float* w_hh0  = (const float*)d_in[2];
    const float* b_ih0  = (const float*)d_in[3];
    const float* b_hh0  = (const float*)d_in[4];
    const float* w_ih1  = (const float*)d_in[5];
    const float* w_hh1  = (const float*)d_in[6];
    const float* b_ih1  = (const float*)d_in[7];
    const float* b_hh1  = (const float*)d_in[8];
    const float* attn_w = (const float*)d_in[9];
    const float* attn_b = (const float*)d_in[10];
    const float* fc_w   = (const float*)d_in[11];
    const float* fc_b   = (const float*)d_in[12];
    float* out = (float*)d_out;

    unsigned short* h1 = (unsigned short*)d_ws;                        // 64 MiB bf16
    unsigned short* o2 = (unsigned short*)((char*)d_ws + 134217728);   // 64 MiB bf16

    gru_l0<<<128, 128, 0, stream>>>(x, w_ih0, w_hh0, b_ih0, b_hh0, h1);
    gru_l1<<<128, 128, 0, stream>>>(h1, w_ih1, w_hh1, b_ih1, b_hh1, o2);
    attn_fc<<<BB, 256, 0, stream>>>(o2, attn_w, attn_b, fc_w, fc_b, out);
}

// Round 20
// 409.640 us; speedup vs baseline: 1.0695x; 1.0695x over previous
//
#include <hip/hip_runtime.h>
#include <math.h>

#define BB 1024
#define TT 512
#define L2E 1.4426950408889634f

typedef __attribute__((ext_vector_type(4))) short  bfx4;
typedef __attribute__((ext_vector_type(8))) short  bfx8;
typedef __attribute__((ext_vector_type(2))) int    int2v;
typedef __attribute__((ext_vector_type(4))) int    int4v;
typedef __attribute__((ext_vector_type(4))) float  floatx4;

__device__ __forceinline__ float fast_rcp(float x){ return __builtin_amdgcn_rcpf(x); }
__device__ __forceinline__ float exp2f_(float x){ return __builtin_amdgcn_exp2f(x); }
__device__ __forceinline__ float sigmoidf_(float x){ return fast_rcp(1.0f + __expf(-x)); }
__device__ __forceinline__ unsigned short f2bf(float f){
    unsigned u = __builtin_bit_cast(unsigned, f);
    u += 0x7fffu + ((u >> 16) & 1u);
    return (unsigned short)(u >> 16);
}
__device__ __forceinline__ float bf2f(unsigned short u){
    return __builtin_bit_cast(float, ((unsigned)u) << 16);
}
__device__ __forceinline__ int cvt_pk_bf16(float lo, float hi){
    int r; asm("v_cvt_pk_bf16_f32 %0, %1, %2" : "=v"(r) : "v"(lo), "v"(hi)); return r;
}
__device__ __forceinline__ floatx4 mfma16(bfx4 a, bfx4 b, floatx4 c){
    return __builtin_amdgcn_mfma_f32_16x16x16bf16_1k(a, b, c, 0, 0, 0);
}
__device__ __forceinline__ floatx4 mfma32(bfx8 a, bfx8 b, floatx4 c){
    return __builtin_amdgcn_mfma_f32_16x16x32_bf16(a, b, c, 0, 0, 0);
}

// sigma(q,j): k-slot order of the feedback B-frag (R10-verified)
__device__ __forceinline__ int sigma_k(int q, int j){
    return (j < 4) ? (q*4 + j) : (16 + q*4 + (j - 4));
}

// lgkm-only workgroup barrier (R1/R14-verified): does NOT drain vmcnt, so
// the named-phase global prefetch stays in flight across steps.
__device__ __forceinline__ void lgkm_barrier(){
    __builtin_amdgcn_sched_barrier(0);
    asm volatile("s_waitcnt lgkmcnt(0)" ::: "memory");
    __builtin_amdgcn_s_barrier();
    __builtin_amdgcn_sched_barrier(0);
}

// ---------------------------------------------------------------------------
// biGRU recurrence, GT-SPLIT across 2 waves (R14-exact, session best):
// wave w owns gate-tile gt=w (channels w*16..w*16+15). Per-wave per-step
// issue halves vs single-wave. Lane-aligned h-exchange: wave w's lane (c,q)
// produces channels w*16+q*4..+3 for batch c = exactly the int2v the other
// wave's lane (c,q) needs for its B-frag k-slots. One ds_write_b64 +
// lgkm-barrier + ds_read_b64 per step, double-buffered.
// ---------------------------------------------------------------------------
__global__ __launch_bounds__(128, 1) void gru_l0(
    const float* __restrict__ x,      // (B,T,4) f32
    const float* __restrict__ w_ih,   // (2,96,4)
    const float* __restrict__ w_hh,   // (2,96,32)
    const float* __restrict__ b_ih,   // (2,96)
    const float* __restrict__ b_hh,   // (2,96)
    unsigned short* __restrict__ h1)  // (B,T,64) bf16
{
    const int tile = blockIdx.x;      // 0..127
    const int bt   = tile >> 1;
    const int d    = tile & 1;
    const int b0   = bt * 16;
    const int w    = threadIdx.x >> 6;   // owned gt
    const int L    = threadIdx.x & 63;
    const int c    = L & 15;
    const int q    = L >> 4;

    // this wave's gt weights only
    bfx8 whh[3];
    bfx4 wih[3];
    #pragma unroll
    for (int g = 0; g < 3; ++g){
        const float sc = (g == 2) ? (2.0f * L2E) : L2E;
        const int row = d*96 + g*32 + w*16 + c;
        bfx8 f;
        #pragma unroll
        for (int j = 0; j < 8; ++j)
            f[j] = f2bf(w_hh[(size_t)row*32 + sigma_k(q, j)] * sc);
        whh[g] = f;
        bfx4 fi = {0,0,0,0};
        if (q == 0){
            #pragma unroll
            for (int j = 0; j < 4; ++j) fi[j] = f2bf(w_ih[(size_t)row*4 + j] * sc);
        }
        wih[g] = fi;
    }
    floatx4 cbr, cbz, cbni, cbhn;
    #pragma unroll
    for (int r = 0; r < 4; ++r){
        const int gidx = d*96 + w*16 + q*4 + r;
        cbr[r]  = L2E * (b_ih[gidx]      + b_hh[gidx]);
        cbz[r]  = L2E * (b_ih[gidx + 32] + b_hh[gidx + 32]);
        cbni[r] = 2.0f * L2E * b_ih[gidx + 64];
        cbhn[r] = 2.0f * L2E * b_hh[gidx + 64];
    }

    __shared__ int2v hx[2][2][64];    // [buf][wave][lane], 2 KB

    float hr[4] = {0.f,0.f,0.f,0.f};
    bfx8 ahc = {0,0,0,0,0,0,0,0};     // full h_{t-1} B-frag (both halves)

    const size_t xrow = (size_t)(b0 + c) * TT;
    float4 xq[4] = {{0,0,0,0},{0,0,0,0},{0,0,0,0},{0,0,0,0}};
    if (q == 0){
        #pragma unroll
        for (int p = 0; p < 4; ++p)
            xq[p] = *(const float4*)(x + (xrow + (d ? TT-1-p : p))*4);
    }

    for (int tb = 0; tb < TT; tb += 4){
        #pragma unroll
        for (int p = 0; p < 4; ++p){
            const int t = tb + p;
            bfx4 ax = {0,0,0,0};
            if (q == 0){
                int2v a; a[0] = cvt_pk_bf16(xq[p].x, xq[p].y); a[1] = cvt_pk_bf16(xq[p].z, xq[p].w);
                ax = __builtin_bit_cast(bfx4, a);
            }
            if (q == 0 && t + 4 < TT)
                xq[p] = *(const float4*)(x + (xrow + (d ? TT-5-t : t+4))*4);

            // x-side (this gt only)
            floatx4 racc  = mfma16(wih[0], ax, cbr);
            floatx4 zacc  = mfma16(wih[1], ax, cbz);
            floatx4 xnacc = mfma16(wih[2], ax, cbni);
            // h-side: ONE sigma-K32 MFMA per gate (full ahc)
            racc          = mfma32(whh[0], ahc, racc);
            zacc          = mfma32(whh[1], ahc, zacc);
            floatx4 hnacc = mfma32(whh[2], ahc, cbhn);

            // gates: 4 elements (i = w*16 + q*4 + r, b = c)
            #pragma unroll
            for (int r = 0; r < 4; ++r){
                const float pp = 1.0f + exp2f_(-racc[r]);
                const float qd = 1.0f + exp2f_(-zacc[r]);
                const float s  = fast_rcp(pp * qd);
                const float rg = s * qd;
                const float zg = s * pp;
                const float e2 = exp2f_(xnacc[r] + rg * hnacc[r]);
                const float ng = 1.0f - 2.0f * fast_rcp(e2 + 1.0f);
                hr[r] = ng + zg * (hr[r] - ng);
            }
            int2v own;
            own[0] = cvt_pk_bf16(hr[0], hr[1]);
            own[1] = cvt_pk_bf16(hr[2], hr[3]);

            // global store of this half (fire-and-forget)
            const int tx = d ? (TT-1-t) : t;
            *(int2v*)(&h1[((size_t)(b0 + c)*TT + tx)*64 + d*32 + w*16 + q*4]) = own;

            // cross-wave exchange (double-buffered, lgkm-only barrier)
            const int wb = t & 1;
            hx[wb][w][L] = own;
            lgkm_barrier();
            const int2v oth = hx[wb][1 - w][L];

            int4v comb;
            if (w == 0){ comb[0] = own[0]; comb[1] = own[1]; comb[2] = oth[0]; comb[3] = oth[1]; }
            else       { comb[0] = oth[0]; comb[1] = oth[1]; comb[2] = own[0]; comb[3] = own[1]; }
            ahc = __builtin_bit_cast(bfx8, comb);
        }
    }
}

// ---------------------------------------------------------------------------
// Layer 1, gt-split (R14-exact): per wave 6 K32 x-projection MFMAs (its gt)
// with 4-phase named prefetch + 3 sigma-K32 h-side MFMAs; same lane-aligned
// LDS h-exchange.
// ---------------------------------------------------------------------------
__global__ __launch_bounds__(128, 1) void gru_l1(
    const unsigned short* __restrict__ h1,   // (B,T,64) bf16
    const float* __restrict__ w_ih,   // (2,96,64)
    const float* __restrict__ w_hh,   // (2,96,32)
    const float* __restrict__ b_ih,   // (2,96)
    const float* __restrict__ b_hh,   // (2,96)
    unsigned short* __restrict__ out2) // (B,T,64) bf16
{
    const int tile = blockIdx.x;
    const int bt   = tile >> 1;
    const int d    = tile & 1;
    const int b0   = bt * 16;
    const int w    = threadIdx.x >> 6;
    const int L    = threadIdx.x & 63;
    const int c    = L & 15;
    const int q    = L >> 4;

    bfx8 whh[3], wi0[3], wi1[3];
    #pragma unroll
    for (int g = 0; g < 3; ++g){
        const float sc = (g == 2) ? (2.0f * L2E) : L2E;
        const int row = d*96 + g*32 + w*16 + c;
        bfx8 f, g0, g1;
        #pragma unroll
        for (int j = 0; j < 8; ++j){
            f[j]  = f2bf(w_hh[(size_t)row*32 + sigma_k(q, j)] * sc);
            g0[j] = f2bf(w_ih[(size_t)row*64 +      q*8 + j] * sc);
            g1[j] = f2bf(w_ih[(size_t)row*64 + 32 + q*8 + j] * sc);
        }
        whh[g] = f; wi0[g] = g0; wi1[g] = g1;
    }
    floatx4 cbr, cbz, cbni, cbhn;
    #pragma unroll
    for (int r = 0; r < 4; ++r){
        const int gidx = d*96 + w*16 + q*4 + r;
        cbr[r]  = L2E * (b_ih[gidx]      + b_hh[gidx]);
        cbz[r]  = L2E * (b_ih[gidx + 32] + b_hh[gidx + 32]);
        cbni[r] = 2.0f * L2E * b_ih[gidx + 64];
        cbhn[r] = 2.0f * L2E * b_hh[gidx + 64];
    }

    __shared__ int2v hx[2][2][64];

    float hr[4] = {0.f,0.f,0.f,0.f};
    bfx8 ahc = {0,0,0,0,0,0,0,0};

    const size_t arow = (size_t)(b0 + c) * TT;
    bfx8 A0[4], A1[4];
    #pragma unroll
    for (int p = 0; p < 4; ++p){
        const int tx = d ? TT-1-p : p;
        A0[p] = *(const bfx8*)(&h1[(arow + tx)*64 +      q*8]);
        A1[p] = *(const bfx8*)(&h1[(arow + tx)*64 + 32 + q*8]);
    }

    for (int tb = 0; tb < TT; tb += 4){
        #pragma unroll
        for (int p = 0; p < 4; ++p){
            const int t = tb + p;

            floatx4 racc  = mfma32(wi0[0], A0[p], cbr);
            racc          = mfma32(wi1[0], A1[p], racc);
            floatx4 zacc  = mfma32(wi0[1], A0[p], cbz);
            zacc          = mfma32(wi1[1], A1[p], zacc);
            floatx4 xnacc = mfma32(wi0[2], A0[p], cbni);
            xnacc         = mfma32(wi1[2], A1[p], xnacc);

            if (t + 4 < TT){
                const int tx4 = d ? (TT-5-t) : (t+4);
                A0[p] = *(const bfx8*)(&h1[(arow + tx4)*64 +      q*8]);
                A1[p] = *(const bfx8*)(&h1[(arow + tx4)*64 + 32 + q*8]);
            }

            racc          = mfma32(whh[0], ahc, racc);
            zacc          = mfma32(whh[1], ahc, zacc);
            floatx4 hnacc = mfma32(whh[2], ahc, cbhn);

            #pragma unroll
            for (int r = 0; r < 4; ++r){
                const float pp = 1.0f + exp2f_(-racc[r]);
                const float qd = 1.0f + exp2f_(-zacc[r]);
                const float s  = fast_rcp(pp * qd);
                const float rg = s * qd;
                const float zg = s * pp;
                const float e2 = exp2f_(xnacc[r] + rg * hnacc[r]);
                const float ng = 1.0f - 2.0f * fast_rcp(e2 + 1.0f);
                hr[r] = ng + zg * (hr[r] - ng);
            }
            int2v own;
            own[0] = cvt_pk_bf16(hr[0], hr[1]);
            own[1] = cvt_pk_bf16(hr[2], hr[3]);

            const int tx = d ? (TT-1-t) : t;
            *(int2v*)(&out2[((size_t)(b0 + c)*TT + tx)*64 + d*32 + w*16 + q*4]) = own;

            const int wb = t & 1;
            hx[wb][w][L] = own;
            lgkm_barrier();
            const int2v oth = hx[wb][1 - w][L];

            int4v comb;
            if (w == 0){ comb[0] = own[0]; comb[1] = own[1]; comb[2] = oth[0]; comb[3] = oth[1]; }
            else       { comb[0] = oth[0]; comb[1] = oth[1]; comb[2] = own[0]; comb[3] = own[1]; }
            ahc = __builtin_bit_cast(bfx8, comb);
        }
    }
}

// ---------------------------------------------------------------------------
// Attention pooling + FC + sigmoid, v4 (R14-exact, session best): one-pass
// online softmax, transposed lane mapping — 8 lanes per row, 16B vector
// loads, 3-shfl reduce.
// ---------------------------------------------------------------------------
__global__ __launch_bounds__(256) void attn_fc(
    const unsigned short* __restrict__ out2, // (B,T,64) bf16
    const float* __restrict__ attn_w, const float* __restrict__ attn_b,
    const float* __restrict__ fc_w,   const float* __restrict__ fc_b,
    float* __restrict__ out)
{
    const int b    = blockIdx.x;
    const int tid  = threadIdx.x;
    const int wave = tid >> 6;      // 0..3
    const int lane = tid & 63;
    const int sub  = lane >> 3;     // row-slot within wave, 0..7
    const int cg   = lane & 7;      // channel-group, 0..7
    const int st   = wave*8 + sub;  // stream id, 0..31

    __shared__ float m_sh[32], s_sh[32];
    __shared__ float acc_sh[32][64];

    float aw[8];
    #pragma unroll
    for (int j = 0; j < 8; ++j) aw[j] = attn_w[cg*8 + j];
    const float ab = attn_b[0];

    float m = -INFINITY, s = 0.0f;
    float acc[8] = {0,0,0,0,0,0,0,0};

    for (int t = st; t < TT; t += 32){
        const bfx8 v8 = *(const bfx8*)(&out2[((size_t)b*TT + t)*64 + cg*8]);
        float v[8];
        #pragma unroll
        for (int j = 0; j < 8; ++j) v[j] = bf2f((unsigned short)v8[j]);
        float p = v[0]*aw[0];
        #pragma unroll
        for (int j = 1; j < 8; ++j) p += v[j]*aw[j];
        p += __shfl_xor(p, 1, 64);
        p += __shfl_xor(p, 2, 64);
        p += __shfl_xor(p, 4, 64);
        const float logit = p + ab;
        const float nm = fmaxf(m, logit);
        const float cs = exp2f_((m - nm) * L2E);      // 0 on first iter
        const float ce = exp2f_((logit - nm) * L2E);
        s = s * cs + ce;
        #pragma unroll
        for (int j = 0; j < 8; ++j) acc[j] = acc[j]*cs + ce*v[j];
        m = nm;
    }
    if (cg == 0){ m_sh[st] = m; s_sh[st] = s; }
    #pragma unroll
    for (int j = 0; j < 8; ++j) acc_sh[st][cg*8 + j] = acc[j];
    __syncthreads();

    if (wave == 0){
        float M = m_sh[0];
        #pragma unroll
        for (int w = 1; w < 32; ++w) M = fmaxf(M, m_sh[w]);
        float S = 0.0f, ctx = 0.0f;
        #pragma unroll 4
        for (int w = 0; w < 32; ++w){
            const float cw = exp2f_((m_sh[w] - M) * L2E);
            S   += s_sh[w] * cw;
            ctx += acc_sh[w][lane] * cw;
        }
        float v = ctx * fast_rcp(S) * fc_w[lane];
        #pragma unroll
        for (int off = 32; off > 0; off >>= 1) v += __shfl_xor(v, off, 64);
        if (lane == 0) out[b] = sigmoidf_(v + fc_b[0]);
    }
}

extern "C" void kernel_launch(void* const* d_in, const int* in_sizes, int n_in,
                              void* d_out, int out_size, void* d_ws, size_t ws_size,
                              hipStream_t stream) {
    (void)in_sizes; (void)n_in; (void)out_size; (void)ws_size;
    const float* x      = (const float*)d_in[0];
    const float* w_ih0  = (const float*)d_in[1];
    const float* w_hh0  = (const float*)d_in[2];
    const float* b_ih0  = (const float*)d_in[3];
    const float* b_hh0  = (const float*)d_in[4];
    const float* w_ih1  = (const float*)d_in[5];
    const float* w_hh1  = (const float*)d_in[6];
    const float* b_ih1  = (const float*)d_in[7];
    const float* b_hh1  = (const float*)d_in[8];
    const float* attn_w = (const float*)d_in[9];
    const float* attn_b = (const float*)d_in[10];
    const float* fc_w   = (const float*)d_in[11];
    const float* fc_b   = (const float*)d_in[12];
    float* out = (float*)d_out;

    unsigned short* h1 = (unsigned short*)d_ws;                        // 67.1 MB bf16
    unsigned short* o2 = (unsigned short*)((char*)d_ws + 134217728);   // 67.1 MB bf16

    gru_l0<<<128, 128, 0, stream>>>(x, w_ih0, w_hh0, b_ih0, b_hh0, h1);
    gru_l1<<<128, 128, 0, stream>>>(h1, w_ih1, w_hh1, b_ih1, b_hh1, o2);
    attn_fc<<<BB, 256, 0, stream>>>(o2, attn_w, attn_b, fc_w, fc_b, out);
}